// Round 11
// baseline (22.536 us; speedup 1.0000x reference)
//
#include <hip/hip_runtime.h>

#define HW_TOT (2048 * 2048)
#define KLAB 32
#define NLAB 16
#define NBIN (NLAB * KLAB)   // 512
#define NBLK 256             // k1 grid: 1 block/CU, 16 waves each
#define BTHR 1024            // threads per k1 block

typedef int   vint4   __attribute__((ext_vector_type(4)));
typedef float vfloat4 __attribute__((ext_vector_type(4)));

// ws layout (every byte store-overwritten each call -> no memset):
//   [0)       u32 hist1[NBLK][NBIN/2]  256 KB  (packed u16 pairs: bins 2c,2c+1)
//   [262144)  float4 parts[NBLK]         4 KB

__global__ __launch_bounds__(BTHR) void connect_k1(
    const vint4* __restrict__ pim, const vfloat4* __restrict__ ps,
    const vfloat4* __restrict__ co, const vint4* __restrict__ tm,
    float4* __restrict__ parts, unsigned int* __restrict__ hist1, int nvec)
{
    __shared__ unsigned int lh[NBIN];
    __shared__ float red[16][4];

    if (threadIdx.x < NBIN) lh[threadIdx.x] = 0u;
    __syncthreads();

    float s2 = 0.f, sp = 0.f, spt = 0.f, sbce = 0.f;

    const int stride = gridDim.x * blockDim.x;  // 262144
    for (int i = blockIdx.x * blockDim.x + threadIdx.x; i < nvec; i += stride) {
        vint4   pv = pim[i];   // plain loads: let replays hit L3/L2
        vfloat4 sv = ps[i];
        vfloat4 cv = co[i];
        vint4   tv = tm[i];

#pragma unroll
        for (int e = 0; e < 4; ++e) {
            float s = sv[e];
            float p = cv[e];
            int   t = tv[e];
            int   k = pv[e];

            s2 += s * s;
            sp += p;
            bool tb = (t > 0);
            float sel = tb ? p : (1.0f - p);
            float lg = fmaxf(__logf(sel), -100.0f);
            sbce += lg;
            if (tb) spt += p;

            atomicAdd(&lh[t * KLAB + k], 1u);
        }
    }

    // wave-level reduce of scalar partials (16 waves)
#pragma unroll
    for (int off = 32; off > 0; off >>= 1) {
        s2   += __shfl_down(s2, off);
        sp   += __shfl_down(sp, off);
        spt  += __shfl_down(spt, off);
        sbce += __shfl_down(sbce, off);
    }
    int wave = threadIdx.x >> 6;
    if ((threadIdx.x & 63) == 0) {
        red[wave][0] = s2; red[wave][1] = sp; red[wave][2] = spt; red[wave][3] = sbce;
    }
    __syncthreads();  // red written AND all LDS histogram atomics complete

    if (threadIdx.x == 0) {
        float4 r = {0.f, 0.f, 0.f, 0.f};
#pragma unroll
        for (int w = 0; w < 16; ++w) {
            r.x += red[w][0]; r.y += red[w][1]; r.z += red[w][2]; r.w += red[w][3];
        }
        parts[blockIdx.x] = r;
    }

    // store-only flush: pack two u16 counts per u32 (per-block max 16384 < 65536)
    if (threadIdx.x < NBIN / 2) {
        unsigned int w = lh[2 * threadIdx.x] | (lh[2 * threadIdx.x + 1] << 16);
        hist1[blockIdx.x * (NBIN / 2) + threadIdx.x] = w;
    }
}

__global__ __launch_bounds__(1024) void connect_fin(
    const unsigned int* __restrict__ hist1, const float4* __restrict__ parts,
    float* __restrict__ out)
{
    __shared__ unsigned int ph[4][NBIN];  // [block-chunk][bin]
    __shared__ float  fh[NBIN];
    __shared__ double sred[4][4];
    __shared__ float  rowmin[NLAB];
    __shared__ float  strow[NLAB];

    int tid = threadIdx.x;

    // ---- reduce packed u16 histograms: 4 chunks x 256 bin-pair columns ----
    {
        int col   = tid & 255;           // bin-pair (bins 2col, 2col+1)
        int chunk = tid >> 8;            // 0..3 -> blocks chunk*64 .. +64
        unsigned int s0 = 0u, s1 = 0u;
#pragma unroll 16
        for (int b = chunk * 64; b < chunk * 64 + 64; ++b) {
            unsigned int w = hist1[b * (NBIN / 2) + col];
            s0 += w & 0xFFFFu;
            s1 += w >> 16;
        }
        ph[chunk][2 * col]     = s0;
        ph[chunk][2 * col + 1] = s1;
    }

    // ---- reduce per-block scalar partials (blocks 0..255 on waves 0..3) ----
    double d2 = 0.0, dp = 0.0, dpt = 0.0, dbce = 0.0;
    if (tid < NBLK) {
        float4 r = parts[tid];
        d2 = r.x; dp = r.y; dpt = r.z; dbce = r.w;
    }
#pragma unroll
    for (int off = 32; off > 0; off >>= 1) {
        d2   += __shfl_down(d2, off);
        dp   += __shfl_down(dp, off);
        dpt  += __shfl_down(dpt, off);
        dbce += __shfl_down(dbce, off);
    }
    if (tid < NBLK && (tid & 63) == 0) {
        int w = tid >> 6;
        sred[w][0] = d2; sred[w][1] = dp; sred[w][2] = dpt; sred[w][3] = dbce;
    }
    __syncthreads();

    if (tid < NBIN)
        fh[tid] = (float)(ph[0][tid] + ph[1][tid] + ph[2][tid] + ph[3][tid]);
    __syncthreads();

    // ---- pair matrix: one thread per (n,k) bin, threads 0..511 ----
    if (tid < NBIN) {
        int n = tid >> 5;
        int k = tid & 31;

        float st = 0.f, spk = 0.f;
#pragma unroll
        for (int kk = 0; kk < KLAB; ++kk) st += fh[n * KLAB + kk];
#pragma unroll
        for (int nn = 0; nn < NLAB; ++nn) spk += fh[nn * KLAB + k];

        float I   = fh[n * KLAB + k];
        float uni = st + spk;
        float pair = 100.0f * (uni - 2.0f * I) / (float)HW_TOT
                   + 1.0f - (2.0f * I + 1.0f) / (uni + 1.0f);

        float v = pair;
#pragma unroll
        for (int off = 16; off > 0; off >>= 1) v = fminf(v, __shfl_xor(v, off));

        if (k == 0) { rowmin[n] = v; strow[n] = st; }
    }
    __syncthreads();

    if (tid == 0) {
        double S2 = 0, SP = 0, SPT = 0, SBCE = 0;
#pragma unroll
        for (int w = 0; w < 4; ++w) {
            S2 += sred[w][0]; SP += sred[w][1]; SPT += sred[w][2]; SBCE += sred[w][3];
        }
        double hw = (double)HW_TOT;
        double res = S2 / hw;                 // MSE(pred_score, 0)
        res += -SBCE / hw;                    // BCE(cls_out, t)
        double sum_t = hw - (double)strow[0]; // count(target > 0)
        res += 1.0 - (2.0 * SPT + 1.0) / (SP + sum_t + 1.0);
        float pm = 0.f;
#pragma unroll
        for (int i = 0; i < NLAB; ++i) pm += rowmin[i];
        res += (double)pm;
        out[0] = (float)(res / (double)NLAB);
    }
}

extern "C" void kernel_launch(void* const* d_in, const int* in_sizes, int n_in,
                              void* d_out, int out_size, void* d_ws, size_t ws_size,
                              hipStream_t stream) {
    const vint4*   pim = (const vint4*)d_in[0];
    const vfloat4* ps  = (const vfloat4*)d_in[1];
    const vfloat4* co  = (const vfloat4*)d_in[2];
    const vint4*   tm  = (const vint4*)d_in[3];
    float* out = (float*)d_out;

    unsigned int* hist1 = (unsigned int*)d_ws;                         // 256 KB
    float4*       parts = (float4*)((char*)d_ws + (size_t)NBLK * (NBIN / 2) * 4);

    const int nvec = HW_TOT / 4;
    connect_k1<<<NBLK, BTHR, 0, stream>>>(pim, ps, co, tm, parts, hist1, nvec);
    connect_fin<<<1, 1024, 0, stream>>>(hist1, parts, out);
}

// Round 12
// 19.942 us; speedup vs baseline: 1.1301x; 1.1301x over previous
//
#include <hip/hip_runtime.h>

#define HW_TOT (2048 * 2048)
#define KLAB 32
#define NLAB 16
#define NBIN (NLAB * KLAB)   // 512
#define NBLK 256             // k1 grid: 1 block/CU, 16 waves each
#define BTHR 1024            // threads per k1 block

typedef int   vint4   __attribute__((ext_vector_type(4)));
typedef float vfloat4 __attribute__((ext_vector_type(4)));

// ws layout (every byte store-overwritten each call -> no memset):
//   [0)       u32 hist1[NBLK][NBIN/2]  256 KB  (packed u16 pairs: bins 2c,2c+1)
//   [262144)  float4 parts[NBLK]         4 KB

__global__ __launch_bounds__(BTHR) void connect_k1(
    const vint4* __restrict__ pim, const vfloat4* __restrict__ ps,
    const vfloat4* __restrict__ co, const vint4* __restrict__ tm,
    float4* __restrict__ parts, unsigned int* __restrict__ hist1, int nvec)
{
    __shared__ unsigned int lh[NBIN];
    __shared__ float red[16][4];

    if (threadIdx.x < NBIN) lh[threadIdx.x] = 0u;
    __syncthreads();

    float s2 = 0.f, sp = 0.f, spt = 0.f, sbce = 0.f;

    const int stride = gridDim.x * blockDim.x;  // 262144
    for (int i = blockIdx.x * blockDim.x + threadIdx.x; i < nvec; i += stride) {
        vint4   pv = __builtin_nontemporal_load(&pim[i]);
        vfloat4 sv = __builtin_nontemporal_load(&ps[i]);
        vfloat4 cv = __builtin_nontemporal_load(&co[i]);
        vint4   tv = __builtin_nontemporal_load(&tm[i]);

#pragma unroll
        for (int e = 0; e < 4; ++e) {
            float s = sv[e];
            float p = cv[e];
            int   t = tv[e];
            int   k = pv[e];

            s2 += s * s;
            sp += p;
            bool tb = (t > 0);
            float sel = tb ? p : (1.0f - p);
            float lg = fmaxf(__logf(sel), -100.0f);
            sbce += lg;
            if (tb) spt += p;

            atomicAdd(&lh[t * KLAB + k], 1u);
        }
    }

    // wave-level reduce of scalar partials (16 waves)
#pragma unroll
    for (int off = 32; off > 0; off >>= 1) {
        s2   += __shfl_down(s2, off);
        sp   += __shfl_down(sp, off);
        spt  += __shfl_down(spt, off);
        sbce += __shfl_down(sbce, off);
    }
    int wave = threadIdx.x >> 6;
    if ((threadIdx.x & 63) == 0) {
        red[wave][0] = s2; red[wave][1] = sp; red[wave][2] = spt; red[wave][3] = sbce;
    }
    __syncthreads();  // red written AND all LDS histogram atomics complete

    if (threadIdx.x == 0) {
        float4 r = {0.f, 0.f, 0.f, 0.f};
#pragma unroll
        for (int w = 0; w < 16; ++w) {
            r.x += red[w][0]; r.y += red[w][1]; r.z += red[w][2]; r.w += red[w][3];
        }
        parts[blockIdx.x] = r;
    }

    // store-only flush: pack two u16 counts per u32 (per-block max 16384 < 65536)
    if (threadIdx.x < NBIN / 2) {
        unsigned int w = lh[2 * threadIdx.x] | (lh[2 * threadIdx.x + 1] << 16);
        hist1[blockIdx.x * (NBIN / 2) + threadIdx.x] = w;
    }
}

__global__ __launch_bounds__(1024) void connect_fin(
    const unsigned int* __restrict__ hist1, const float4* __restrict__ parts,
    float* __restrict__ out)
{
    __shared__ unsigned int ph[4][NBIN];  // [block-chunk][bin]
    __shared__ float  fh[NBIN];
    __shared__ double sred[4][4];
    __shared__ float  rowmin[NLAB];
    __shared__ float  strow[NLAB];

    int tid = threadIdx.x;

    // ---- reduce packed u16 histograms: 4 chunks x 256 bin-pair columns ----
    {
        int col   = tid & 255;           // bin-pair (bins 2col, 2col+1)
        int chunk = tid >> 8;            // 0..3 -> blocks chunk*64 .. +64
        unsigned int s0 = 0u, s1 = 0u;
#pragma unroll 16
        for (int b = chunk * 64; b < chunk * 64 + 64; ++b) {
            unsigned int w = hist1[b * (NBIN / 2) + col];
            s0 += w & 0xFFFFu;
            s1 += w >> 16;
        }
        ph[chunk][2 * col]     = s0;
        ph[chunk][2 * col + 1] = s1;
    }

    // ---- reduce per-block scalar partials (blocks 0..255 on waves 0..3) ----
    double d2 = 0.0, dp = 0.0, dpt = 0.0, dbce = 0.0;
    if (tid < NBLK) {
        float4 r = parts[tid];
        d2 = r.x; dp = r.y; dpt = r.z; dbce = r.w;
    }
#pragma unroll
    for (int off = 32; off > 0; off >>= 1) {
        d2   += __shfl_down(d2, off);
        dp   += __shfl_down(dp, off);
        dpt  += __shfl_down(dpt, off);
        dbce += __shfl_down(dbce, off);
    }
    if (tid < NBLK && (tid & 63) == 0) {
        int w = tid >> 6;
        sred[w][0] = d2; sred[w][1] = dp; sred[w][2] = dpt; sred[w][3] = dbce;
    }
    __syncthreads();

    if (tid < NBIN)
        fh[tid] = (float)(ph[0][tid] + ph[1][tid] + ph[2][tid] + ph[3][tid]);
    __syncthreads();

    // ---- pair matrix: one thread per (n,k) bin, threads 0..511 ----
    if (tid < NBIN) {
        int n = tid >> 5;
        int k = tid & 31;

        float st = 0.f, spk = 0.f;
#pragma unroll
        for (int kk = 0; kk < KLAB; ++kk) st += fh[n * KLAB + kk];
#pragma unroll
        for (int nn = 0; nn < NLAB; ++nn) spk += fh[nn * KLAB + k];

        float I   = fh[n * KLAB + k];
        float uni = st + spk;
        float pair = 100.0f * (uni - 2.0f * I) / (float)HW_TOT
                   + 1.0f - (2.0f * I + 1.0f) / (uni + 1.0f);

        float v = pair;
#pragma unroll
        for (int off = 16; off > 0; off >>= 1) v = fminf(v, __shfl_xor(v, off));

        if (k == 0) { rowmin[n] = v; strow[n] = st; }
    }
    __syncthreads();

    if (tid == 0) {
        double S2 = 0, SP = 0, SPT = 0, SBCE = 0;
#pragma unroll
        for (int w = 0; w < 4; ++w) {
            S2 += sred[w][0]; SP += sred[w][1]; SPT += sred[w][2]; SBCE += sred[w][3];
        }
        double hw = (double)HW_TOT;
        double res = S2 / hw;                 // MSE(pred_score, 0)
        res += -SBCE / hw;                    // BCE(cls_out, t)
        double sum_t = hw - (double)strow[0]; // count(target > 0)
        res += 1.0 - (2.0 * SPT + 1.0) / (SP + sum_t + 1.0);
        float pm = 0.f;
#pragma unroll
        for (int i = 0; i < NLAB; ++i) pm += rowmin[i];
        res += (double)pm;
        out[0] = (float)(res / (double)NLAB);
    }
}

extern "C" void kernel_launch(void* const* d_in, const int* in_sizes, int n_in,
                              void* d_out, int out_size, void* d_ws, size_t ws_size,
                              hipStream_t stream) {
    const vint4*   pim = (const vint4*)d_in[0];
    const vfloat4* ps  = (const vfloat4*)d_in[1];
    const vfloat4* co  = (const vfloat4*)d_in[2];
    const vint4*   tm  = (const vint4*)d_in[3];
    float* out = (float*)d_out;

    unsigned int* hist1 = (unsigned int*)d_ws;                         // 256 KB
    float4*       parts = (float4*)((char*)d_ws + (size_t)NBLK * (NBIN / 2) * 4);

    const int nvec = HW_TOT / 4;
    connect_k1<<<NBLK, BTHR, 0, stream>>>(pim, ps, co, tm, parts, hist1, nvec);
    connect_fin<<<1, 1024, 0, stream>>>(hist1, parts, out);
}